// Round 4
// baseline (1269.123 us; speedup 1.0000x reference)
//
#include <hip/hip_runtime.h>
#include <hip/hip_fp16.h>

#define BB 512
#define TT 512
#define EE 100
#define HH 40
#define GG 120   // 3*HH
#define TC 64    // timesteps per chunk
#define NC 8     // chunks

typedef _Float16 h2_t __attribute__((ext_vector_type(2)));

#if defined(__has_builtin)
#if __has_builtin(__builtin_amdgcn_fdot2)
#define HAS_FDOT2 1
#endif
#endif

__device__ __forceinline__ float fdot2_(h2_t a, h2_t b, float c) {
#if defined(HAS_FDOT2)
    return __builtin_amdgcn_fdot2(a, b, c, false);
#else
    return fmaf((float)a[0], (float)b[0], fmaf((float)a[1], (float)b[1], c));
#endif
}
__device__ __forceinline__ h2_t pack2_(float x, float y) {
    h2_t r; r[0] = (_Float16)x; r[1] = (_Float16)y; return r;
}
__device__ __forceinline__ float sigmoid_(float x) {
    return 1.0f / (1.0f + __expf(-x));
}
__device__ __forceinline__ float tanhfast_(float x) {
    float e = __expf(2.0f * x);
    return 1.0f - 2.0f / (e + 1.0f);
}

// Fused launch: blocks [0,nScan) = recurrent scan (chunk cs, reads gxR);
// blocks [nScan,..) = input-side GEMM (chunk cg, writes gxW). No shared data
// between halves -> no ordering assumption (G16-safe).
//
// Scan: ONE WAVE PER BATCH handles BOTH directions (two independent
// dependency chains interleaved -> latency of one hides under issue of the
// other). Lane j (<40) owns channel j of both chains. GEMV via v_dot2 with
// Whh in fp16-packed VGPRs (120 regs), h broadcast via per-wave LDS fp16
// vector (5 x b128 broadcast reads, in-order DS, no barrier). gx prefetched
// one step ahead.
//
// GEMM: k-pair-major fp16 LDS tiles; inner loop = 2 x ds_read_b128 + 16
// v_dot2 per k-pair. 26 KB LDS/block.
template<int K, bool GATHER>
__global__ __launch_bounds__(256) void fused_kernel(
    const int cg, const int cs, const int nScan,
    const int* __restrict__ text, const float* __restrict__ emb,
    const __half* __restrict__ Xh,
    const float* __restrict__ Wf, const float* __restrict__ bf,
    const float* __restrict__ Wb, const float* __restrict__ bb,
    __half* __restrict__ gxW, const __half* __restrict__ gxR,
    const float* __restrict__ WhhF, const float* __restrict__ bhhF,
    const float* __restrict__ WhhB, const float* __restrict__ bhhB,
    const int* __restrict__ lens,
    __half* __restrict__ out0,
    float* __restrict__ hcar, float* __restrict__ hlast,
    float* __restrict__ sumb, float* __restrict__ maxb)
{
    constexpr int K2 = K / 2;
    __shared__ h2_t Xs2[K2 * 64];
    __shared__ h2_t Ws2[K2 * 64];
    __shared__ __align__(16) _Float16 hF[4][HH];
    __shared__ __align__(16) _Float16 hB[4][HH];
    const int tid = threadIdx.x;

    if ((int)blockIdx.x < nScan) {
        // ================= scan: one wave = one batch, both dirs ==========
        const int wave = tid >> 6, j = tid & 63;
        if (j >= HH) return;
        const int b = blockIdx.x * 4 + wave;

        // Whh rows {j, 40+j, 80+j} for both dirs, packed half2 (120 VGPRs)
        h2_t WrF[HH/2], WzF[HH/2], WnF[HH/2], WrB[HH/2], WzB[HH/2], WnB[HH/2];
        {
            const float4* rf = (const float4*)(WhhF + (size_t)(0*HH + j) * HH);
            const float4* zf = (const float4*)(WhhF + (size_t)(1*HH + j) * HH);
            const float4* nf = (const float4*)(WhhF + (size_t)(2*HH + j) * HH);
            const float4* rb = (const float4*)(WhhB + (size_t)(0*HH + j) * HH);
            const float4* zb = (const float4*)(WhhB + (size_t)(1*HH + j) * HH);
            const float4* nb = (const float4*)(WhhB + (size_t)(2*HH + j) * HH);
            #pragma unroll
            for (int q = 0; q < HH/4; ++q) {
                float4 v;
                v = rf[q]; WrF[2*q] = pack2_(v.x,v.y); WrF[2*q+1] = pack2_(v.z,v.w);
                v = zf[q]; WzF[2*q] = pack2_(v.x,v.y); WzF[2*q+1] = pack2_(v.z,v.w);
                v = nf[q]; WnF[2*q] = pack2_(v.x,v.y); WnF[2*q+1] = pack2_(v.z,v.w);
                v = rb[q]; WrB[2*q] = pack2_(v.x,v.y); WrB[2*q+1] = pack2_(v.z,v.w);
                v = zb[q]; WzB[2*q] = pack2_(v.x,v.y); WzB[2*q+1] = pack2_(v.z,v.w);
                v = nb[q]; WnB[2*q] = pack2_(v.x,v.y); WnB[2*q+1] = pack2_(v.z,v.w);
            }
        }
        const float brF = bhhF[j], bzF = bhhF[HH+j], bnF = bhhF[2*HH+j];
        const float brB = bhhB[j], bzB = bhhB[HH+j], bnB = bhhB[2*HH+j];
        const int len = lens[b];
        const int tbF = cs * TC;                // fwd chunk
        const int tbB = (NC - 1 - cs) * TC;     // bwd chunk

        float hfv = (cs == 0) ? 0.0f : hcar[(size_t)(0*BB + b) * HH + j];
        float hbv = (cs == 0) ? 0.0f : hcar[(size_t)(1*BB + b) * HH + j];
        hF[wave][j] = (_Float16)hfv;
        hB[wave][j] = (_Float16)hbv;
        float psF = 0.f, pmF = -3.4e38f, psB = 0.f, pmB = -3.4e38f;
        const size_t rowF = ((size_t)0*BB + b) * TC;
        const size_t rowB = ((size_t)1*BB + b) * TC;

        // prefetch step 0 gx for both chains
        const __half* gpF = gxR + (rowF + 0) * GG;
        const __half* gpB = gxR + (rowB + (TC - 1)) * GG;
        __half rF = gpF[j], zF = gpF[HH+j], nF = gpF[2*HH+j];
        __half rB = gpB[j], zB = gpB[HH+j], nB = gpB[2*HH+j];

        const float4* hf4 = (const float4*)hF[wave];
        const float4* hb4 = (const float4*)hB[wave];
        for (int s = 0; s < TC; ++s) {
            const int tF = tbF + s;
            const int tB = tbB + (TC - 1 - s);
            __half prF = __float2half(0.f), pzF = prF, pnF = prF;
            __half prB = prF, pzB = prF, pnB = prF;
            if (s + 1 < TC) {   // prefetch next step
                const __half* qF = gxR + (rowF + s + 1) * GG;
                const __half* qB = gxR + (rowB + (TC - 2 - s)) * GG;
                prF = qF[j]; pzF = qF[HH+j]; pnF = qF[2*HH+j];
                prB = qB[j]; pzB = qB[HH+j]; pnB = qB[2*HH+j];
            }
            float ghrF = brF, ghzF = bzF, ghnF = bnF;
            float ghrB = brB, ghzB = bzB, ghnB = bnB;
            #pragma unroll
            for (int q = 0; q < 5; ++q) {
                union { float4 f; h2_t h[4]; } uf, ub;
                uf.f = hf4[q]; ub.f = hb4[q];
                #pragma unroll
                for (int i = 0; i < 4; ++i) {
                    const int w = 4*q + i;
                    ghrF = fdot2_(WrF[w], uf.h[i], ghrF);
                    ghzF = fdot2_(WzF[w], uf.h[i], ghzF);
                    ghnF = fdot2_(WnF[w], uf.h[i], ghnF);
                    ghrB = fdot2_(WrB[w], ub.h[i], ghrB);
                    ghzB = fdot2_(WzB[w], ub.h[i], ghzB);
                    ghnB = fdot2_(WnB[w], ub.h[i], ghnB);
                }
            }
            // gates (two independent chains -> ILP)
            const float rrF = sigmoid_(__half2float(rF) + ghrF);
            const float rrB = sigmoid_(__half2float(rB) + ghrB);
            const float zzF = sigmoid_(__half2float(zF) + ghzF);
            const float zzB = sigmoid_(__half2float(zB) + ghzB);
            const float nnF = tanhfast_(__half2float(nF) + rrF * ghnF);
            const float nnB = tanhfast_(__half2float(nB) + rrB * ghnB);
            const float hnF = (1.0f - zzF) * nnF + zzF * hfv;
            const float hnB = (1.0f - zzB) * nnB + zzB * hbv;
            const bool vF = (tF < len), vB = (tB < len);
            hfv = vF ? hnF : hfv;
            hbv = vB ? hnB : hbv;
            const float ovF = vF ? hnF : 0.0f;
            const float ovB = vB ? hnB : 0.0f;
            if (GATHER) {  // layer 0: materialize out0 fp16
                out0[((size_t)b * TT + tF) * (2*HH) + j]      = __float2half(ovF);
                out0[((size_t)b * TT + tB) * (2*HH) + HH + j] = __float2half(ovB);
            } else {       // layer 1: fused pooling
                psF += ovF; if (vF) pmF = fmaxf(pmF, hnF);
                psB += ovB; if (vB) pmB = fmaxf(pmB, hnB);
            }
            hF[wave][j] = (_Float16)hfv;
            hB[wave][j] = (_Float16)hbv;
            rF = prF; zF = pzF; nF = pnF;
            rB = prB; zB = pzB; nB = pnB;
        }
        hcar[(size_t)(0*BB + b) * HH + j] = hfv;
        hcar[(size_t)(1*BB + b) * HH + j] = hbv;
        const int layer = GATHER ? 0 : 1;
        if (cs == NC - 1) {
            hlast[((size_t)(layer*2 + 0) * BB + b) * HH + j] = hfv;
            hlast[((size_t)(layer*2 + 1) * BB + b) * HH + j] = hbv;
        }
        if (!GATHER) {
            const size_t piF = (size_t)b * (2*HH) + j;
            const size_t piB = piF + HH;
            if (cs == 0) { sumb[piF] = psF; maxb[piF] = pmF;
                           sumb[piB] = psB; maxb[piB] = pmB; }
            else { sumb[piF] += psF; maxb[piF] = fmaxf(maxb[piF], pmF);
                   sumb[piB] += psB; maxb[piB] = fmaxf(maxb[piB], pmB); }
        }
        return;
    }

    // ================= gemm (fp16 dot2) =================
    const int gid = blockIdx.x - nScan;
    const int b   = gid & (BB - 1);
    const int ct  = (gid >> 9) & 1;
    const int dir = gid >> 10;
    const int chunk = dir ? (NC - 1 - cg) : cg;
    const int tbase = chunk * TC;
    const float* W    = dir ? Wb : Wf;
    const float* bias = dir ? bb : bf;
    const int c0 = ct * 64;

    // stage X fp16 k-pair-major: Xs2[k2][r]
    if (GATHER) {
        constexpr int KQ = K / 4;
        for (int idx = tid; idx < 64 * KQ; idx += 256) {
            const int r = idx & 63, q = idx >> 6;
            const int tok = text[b * TT + tbase + r];
            const float4 v = ((const float4*)emb)[(size_t)tok * KQ + q];
            Xs2[(2*q+0)*64 + r] = pack2_(v.x, v.y);
            Xs2[(2*q+1)*64 + r] = pack2_(v.z, v.w);
        }
    } else {
        constexpr int KQ8 = K / 8;
        for (int idx = tid; idx < 64 * KQ8; idx += 256) {
            const int r = idx & 63, q = idx >> 6;
            union { float4 f; h2_t h[4]; } u;
            u.f = ((const float4*)Xh)[((size_t)b * TT + tbase + r) * KQ8 + q];
            #pragma unroll
            for (int i2 = 0; i2 < 4; ++i2)
                Xs2[(4*q + i2)*64 + r] = u.h[i2];
        }
    }
    // stage W fp16 k-pair-major: Ws2[k2][c]
    {
        constexpr int KQ = K / 4;
        for (int idx = tid; idx < 64 * KQ; idx += 256) {
            const int c = idx & 63, q = idx >> 6;
            float4 v = make_float4(0.f,0.f,0.f,0.f);
            if (c0 + c < GG) v = ((const float4*)W)[(size_t)(c0 + c) * KQ + q];
            Ws2[(2*q+0)*64 + c] = pack2_(v.x, v.y);
            Ws2[(2*q+1)*64 + c] = pack2_(v.z, v.w);
        }
    }
    __syncthreads();

    const int tx = tid & 15, ty = tid >> 4;
    float acc[4][4] = {};
    #pragma unroll 2
    for (int k2 = 0; k2 < K2; ++k2) {
        union { float4 f; h2_t h[4]; } xa, wv;
        xa.f = *(const float4*)(Xs2 + k2*64 + (ty << 2));
        wv.f = *(const float4*)(Ws2 + k2*64 + (tx << 2));
        #pragma unroll
        for (int i = 0; i < 4; ++i)
            #pragma unroll
            for (int j2 = 0; j2 < 4; ++j2)
                acc[i][j2] = fdot2_(xa.h[i], wv.h[j2], acc[i][j2]);
    }

    const int c = c0 + (tx << 2);
    if (c < GG) {
        const float b0v = bias[c], b1v = bias[c+1], b2v = bias[c+2], b3v = bias[c+3];
        const size_t rowB = ((size_t)dir * BB + b) * TC;
        #pragma unroll
        for (int i = 0; i < 4; ++i) {
            const int tloc = (ty << 2) + i;
            union { float2 f; __half2 h[2]; } u;
            u.h[0] = __floats2half2_rn(acc[i][0] + b0v, acc[i][1] + b1v);
            u.h[1] = __floats2half2_rn(acc[i][2] + b2v, acc[i][3] + b3v);
            *(float2*)(gxW + (rowB + tloc) * GG + c) = u.f;
        }
    }
}

// pool_cat = [hb1, hf1, hb0, hf0, avg(80), max(80)] -> fc1(128) -> lrelu -> fc2(1)
__global__ __launch_bounds__(128) void fc_kernel(
    const float* __restrict__ hlast, const float* __restrict__ sumb,
    const float* __restrict__ maxb, const int* __restrict__ lens,
    const float* __restrict__ fc1W, const float* __restrict__ fc1b,
    const float* __restrict__ fc2W, const float* __restrict__ fc2b,
    float* __restrict__ out)
{
    __shared__ float pool[8 * HH];
    __shared__ float red[128];
    const int b = blockIdx.x, tid = threadIdx.x;
    if (tid < HH) {
        pool[tid]        = hlast[(size_t)(3*BB + b) * HH + tid]; // hb1
        pool[HH + tid]   = hlast[(size_t)(2*BB + b) * HH + tid]; // hf1
        pool[2*HH + tid] = hlast[(size_t)(1*BB + b) * HH + tid]; // hb0
        pool[3*HH + tid] = hlast[(size_t)(0*BB + b) * HH + tid]; // hf0
    }
    const float invLen = 1.0f / (float)lens[b];
    if (tid < 2*HH) {
        pool[4*HH + tid] = sumb[(size_t)b * 2*HH + tid] * invLen;
        pool[6*HH + tid] = maxb[(size_t)b * 2*HH + tid];
    }
    __syncthreads();
    float acc = fc1b[tid];
    for (int k = 0; k < 8*HH; ++k)
        acc = fmaf(pool[k], fc1W[(size_t)tid * (8*HH) + k], acc);
    float v = (acc >= 0.0f) ? acc : 0.01f * acc;
    red[tid] = v * fc2W[tid];
    __syncthreads();
    for (int s = 64; s > 0; s >>= 1) {
        if (tid < s) red[tid] += red[tid + s];
        __syncthreads();
    }
    if (tid == 0) out[b] = red[0] + fc2b[0];
}

extern "C" void kernel_launch(void* const* d_in, const int* in_sizes, int n_in,
                              void* d_out, int out_size, void* d_ws, size_t ws_size,
                              hipStream_t stream) {
    const int*   text  = (const int*)d_in[0];
    const int*   lens  = (const int*)d_in[1];
    const float* emb   = (const float*)d_in[2];
    const float* Wih0f = (const float*)d_in[3];
    const float* Whh0f = (const float*)d_in[4];
    const float* bih0f = (const float*)d_in[5];
    const float* bhh0f = (const float*)d_in[6];
    const float* Wih0b = (const float*)d_in[7];
    const float* Whh0b = (const float*)d_in[8];
    const float* bih0b = (const float*)d_in[9];
    const float* bhh0b = (const float*)d_in[10];
    const float* Wih1f = (const float*)d_in[11];
    const float* Whh1f = (const float*)d_in[12];
    const float* bih1f = (const float*)d_in[13];
    const float* bhh1f = (const float*)d_in[14];
    const float* Wih1b = (const float*)d_in[15];
    const float* Whh1b = (const float*)d_in[16];
    const float* bih1b = (const float*)d_in[17];
    const float* bhh1b = (const float*)d_in[18];
    const float* fc1W  = (const float*)d_in[19];
    const float* fc1b  = (const float*)d_in[20];
    const float* fc2W  = (const float*)d_in[21];
    const float* fc2b  = (const float*)d_in[22];
    float* out = (float*)d_out;

    // ws: gx double-buffer fp16 (2 x 15.73MB) | out0 fp16 (41.94MB) | small
    char* p = (char*)d_ws;
    const size_t gxB = (size_t)2 * BB * TC * GG * sizeof(__half);
    __half* gxb0  = (__half*)p;  p += gxB;
    __half* gxb1  = (__half*)p;  p += gxB;
    __half* out0  = (__half*)p;  p += (size_t)BB * TT * 2 * HH * sizeof(__half);
    float*  hcar  = (float*)p;   p += (size_t)2 * BB * HH * sizeof(float);
    float*  hlast = (float*)p;   p += (size_t)4 * BB * HH * sizeof(float);
    float*  sumb  = (float*)p;   p += (size_t)BB * 2 * HH * sizeof(float);
    float*  maxb  = (float*)p;
    __half* gxb[2] = { gxb0, gxb1 };

    const int NG = BB * 2 * 2;   // 2048 gemm blocks
    const int NS = 128;          // 512 batches / 4 waves; each wave = both dirs

    // ---- layer 0 ----
    fused_kernel<EE, true><<<NG, 256, 0, stream>>>(0, 0, 0,
        text, emb, nullptr, Wih0f, bih0f, Wih0b, bih0b,
        gxb[0], gxb[0], Whh0f, bhh0f, Whh0b, bhh0b,
        lens, out0, hcar, hlast, sumb, maxb);
    for (int ci = 1; ci < NC; ++ci)
        fused_kernel<EE, true><<<NS + NG, 256, 0, stream>>>(ci, ci - 1, NS,
            text, emb, nullptr, Wih0f, bih0f, Wih0b, bih0b,
            gxb[ci & 1], gxb[(ci - 1) & 1], Whh0f, bhh0f, Whh0b, bhh0b,
            lens, out0, hcar, hlast, sumb, maxb);
    fused_kernel<EE, true><<<NS, 256, 0, stream>>>(0, NC - 1, NS,
        text, emb, nullptr, Wih0f, bih0f, Wih0b, bih0b,
        gxb[0], gxb[(NC - 1) & 1], Whh0f, bhh0f, Whh0b, bhh0b,
        lens, out0, hcar, hlast, sumb, maxb);

    // ---- layer 1 ----
    fused_kernel<2*HH, false><<<NG, 256, 0, stream>>>(0, 0, 0,
        text, emb, out0, Wih1f, bih1f, Wih1b, bih1b,
        gxb[0], gxb[0], Whh1f, bhh1f, Whh1b, bhh1b,
        lens, out0, hcar, hlast, sumb, maxb);
    for (int ci = 1; ci < NC; ++ci)
        fused_kernel<2*HH, false><<<NS + NG, 256, 0, stream>>>(ci, ci - 1, NS,
            text, emb, out0, Wih1f, bih1f, Wih1b, bih1b,
            gxb[ci & 1], gxb[(ci - 1) & 1], Whh1f, bhh1f, Whh1b, bhh1b,
            lens, out0, hcar, hlast, sumb, maxb);
    fused_kernel<2*HH, false><<<NS, 256, 0, stream>>>(0, NC - 1, NS,
        text, emb, out0, Wih1f, bih1f, Wih1b, bih1b,
        gxb[0], gxb[(NC - 1) & 1], Whh1f, bhh1f, Whh1b, bhh1b,
        lens, out0, hcar, hlast, sumb, maxb);

    // ---- head ----
    fc_kernel<<<BB, 128, 0, stream>>>(hlast, sumb, maxb, lens,
        fc1W, fc1b, fc2W, fc2b, out);
}

// Round 5
// 764.547 us; speedup vs baseline: 1.6600x; 1.6600x over previous
//
#include <hip/hip_runtime.h>
#include <hip/hip_fp16.h>

#define BB 512
#define TT 512
#define EE 100
#define HH 40
#define GG 120   // 3*HH
#define TC 64    // timesteps per chunk
#define NC 8     // chunks

typedef _Float16 h2_t __attribute__((ext_vector_type(2)));

__device__ __forceinline__ float fdot2_(h2_t a, h2_t b, float c) {
    return __builtin_amdgcn_fdot2(a, b, c, false);
}
__device__ __forceinline__ h2_t pack2_(float x, float y) {
    h2_t r; r[0] = (_Float16)x; r[1] = (_Float16)y; return r;
}
__device__ __forceinline__ float sigmoid_(float x) {
    return 1.0f / (1.0f + __expf(-x));
}
__device__ __forceinline__ float tanhfast_(float x) {
    float e = __expf(2.0f * x);
    return 1.0f - 2.0f / (e + 1.0f);
}

// Fused launch: blocks [0,nScan) = recurrent scan (chunk cs, reads gxR);
// blocks [nScan,..) = input GEMM (chunk cg, writes gxW). Halves share no
// data -> no ordering assumption (G16-safe).
//
// Scan: one wave per (batch,dir) chain. Lane j<40 owns channel j; Whh rows
// {j,40+j,80+j} fp16-packed in 60 VGPRs (the round3/4 spill fix:
// __launch_bounds__(256,2) caps VGPR at 256, so these stay RESIDENT —
// at launch_bounds(256) the allocator capped at 84/132 and reloaded weights
// from scratch every step, 4x slower). h broadcast via per-wave LDS fp16
// vector (5 b128 broadcast reads, in-order DS, no barrier). gx prefetched
// one step ahead. Dot chains split into 2 partial accumulators (depth 10).
//
// GEMM: k-pair-major fp16 LDS tiles; 2 x ds_read_b128 + 16 v_dot2 per
// k-pair; 26 KB LDS/block.
template<int K, bool GATHER>
__global__ __launch_bounds__(256, 2) void fused_kernel(
    const int cg, const int cs, const int nScan,
    const int* __restrict__ text, const float* __restrict__ emb,
    const __half* __restrict__ Xh,
    const float* __restrict__ Wf, const float* __restrict__ bf,
    const float* __restrict__ Wb, const float* __restrict__ bb,
    __half* __restrict__ gxW, const __half* __restrict__ gxR,
    const float* __restrict__ WhhF, const float* __restrict__ bhhF,
    const float* __restrict__ WhhB, const float* __restrict__ bhhB,
    const int* __restrict__ lens,
    __half* __restrict__ out0,
    float* __restrict__ hcar, float* __restrict__ hlast,
    float* __restrict__ sumb, float* __restrict__ maxb)
{
    constexpr int K2 = K / 2;
    __shared__ h2_t Xs2[K2 * 64];
    __shared__ h2_t Ws2[K2 * 64];
    __shared__ __align__(16) _Float16 hsh[4][48];
    const int tid = threadIdx.x;

    if ((int)blockIdx.x < nScan) {
        // ============ scan: one wave = one (batch,dir) chain ============
        const int wave = tid >> 6, j = tid & 63;
        if (j >= HH) return;
        const int chain = blockIdx.x * 4 + wave;   // 0..1023
        const int dir = chain >> 9;
        const int b   = chain & (BB - 1);
        const float* Whh = dir ? WhhB : WhhF;
        const float* bhh = dir ? bhhB : bhhF;

        // Whh rows {j,40+j,80+j} packed half2: 60 VGPRs, stays resident
        h2_t Wr[HH/2], Wz[HH/2], Wn[HH/2];
        {
            const float4* r4 = (const float4*)(Whh + (size_t)(0*HH + j) * HH);
            const float4* z4 = (const float4*)(Whh + (size_t)(1*HH + j) * HH);
            const float4* n4 = (const float4*)(Whh + (size_t)(2*HH + j) * HH);
            #pragma unroll
            for (int q = 0; q < HH/4; ++q) {
                float4 v;
                v = r4[q]; Wr[2*q] = pack2_(v.x,v.y); Wr[2*q+1] = pack2_(v.z,v.w);
                v = z4[q]; Wz[2*q] = pack2_(v.x,v.y); Wz[2*q+1] = pack2_(v.z,v.w);
                v = n4[q]; Wn[2*q] = pack2_(v.x,v.y); Wn[2*q+1] = pack2_(v.z,v.w);
            }
        }
        const float br = bhh[j], bz = bhh[HH + j], bn = bhh[2*HH + j];
        const int len = lens[b];
        const int chunk = dir ? (NC - 1 - cs) : cs;
        const int tbase = chunk * TC;

        float h = (cs == 0) ? 0.0f : hcar[(size_t)(dir * BB + b) * HH + j];
        hsh[wave][j] = (_Float16)h;
        float psum = 0.0f, pmax = -3.4e38f;
        const size_t gxRow = ((size_t)dir * BB + b) * TC;

        const __half* gp0 = gxR + (gxRow + (dir ? (TC - 1) : 0)) * GG;
        __half rH = gp0[j], zH = gp0[HH + j], nH = gp0[2*HH + j];

        const float4* h4 = (const float4*)hsh[wave];
        for (int s = 0; s < TC; ++s) {
            const int tloc = dir ? (TC - 1 - s) : s;
            const int t = tbase + tloc;
            __half prH = __float2half(0.f), pzH = prH, pnH = prH;
            if (s + 1 < TC) {   // prefetch next step's gx
                const __half* gq = gxR + (gxRow + (dir ? (TC - 2 - s) : (s + 1))) * GG;
                prH = gq[j]; pzH = gq[HH + j]; pnH = gq[2*HH + j];
            }
            // GEMV: 60 dot2, two partial accumulators per gate (depth 10)
            float r0 = br, r1 = 0.f, z0 = bz, z1 = 0.f, n0 = bn, n1 = 0.f;
            #pragma unroll
            for (int q = 0; q < 5; ++q) {
                union { float4 f; h2_t h[4]; } u;
                u.f = h4[q];
                #pragma unroll
                for (int i = 0; i < 4; ++i) {
                    const int w = 4*q + i;
                    if (w & 1) {
                        r1 = fdot2_(Wr[w], u.h[i], r1);
                        z1 = fdot2_(Wz[w], u.h[i], z1);
                        n1 = fdot2_(Wn[w], u.h[i], n1);
                    } else {
                        r0 = fdot2_(Wr[w], u.h[i], r0);
                        z0 = fdot2_(Wz[w], u.h[i], z0);
                        n0 = fdot2_(Wn[w], u.h[i], n0);
                    }
                }
            }
            const float ghr = r0 + r1, ghz = z0 + z1, ghn = n0 + n1;
            const float rr = sigmoid_(__half2float(rH) + ghr);
            const float zz = sigmoid_(__half2float(zH) + ghz);
            const float nn = tanhfast_(__half2float(nH) + rr * ghn);
            const float hn = (1.0f - zz) * nn + zz * h;
            const bool v = (t < len);
            h = v ? hn : h;
            const float ov = v ? hn : 0.0f;
            if (GATHER) {  // layer 0: materialize out0 fp16
                out0[((size_t)b * TT + t) * (2*HH) + dir*HH + j] = __float2half(ov);
            } else {       // layer 1: fused pooling
                psum += ov;
                if (v) pmax = fmaxf(pmax, hn);
            }
            hsh[wave][j] = (_Float16)h;   // broadcast for next step
            rH = prH; zH = pzH; nH = pnH;
        }
        hcar[(size_t)(dir * BB + b) * HH + j] = h;
        const int layer = GATHER ? 0 : 1;
        if (cs == NC - 1)
            hlast[((size_t)(layer * 2 + dir) * BB + b) * HH + j] = h;
        if (!GATHER) {
            const size_t pi = (size_t)b * (2*HH) + dir*HH + j;
            if (cs == 0) { sumb[pi] = psum;  maxb[pi] = pmax; }
            else         { sumb[pi] += psum; maxb[pi] = fmaxf(maxb[pi], pmax); }
        }
        return;
    }

    // ================= gemm (fp16 dot2) =================
    const int gid = blockIdx.x - nScan;
    const int b   = gid & (BB - 1);
    const int ct  = (gid >> 9) & 1;
    const int dir = gid >> 10;
    const int chunk = dir ? (NC - 1 - cg) : cg;
    const int tbase = chunk * TC;
    const float* W    = dir ? Wb : Wf;
    const float* bias = dir ? bb : bf;
    const int c0 = ct * 64;

    // stage X fp16 k-pair-major: Xs2[k2][r]
    if (GATHER) {
        constexpr int KQ = K / 4;
        for (int idx = tid; idx < 64 * KQ; idx += 256) {
            const int r = idx & 63, q = idx >> 6;
            const int tok = text[b * TT + tbase + r];
            const float4 v = ((const float4*)emb)[(size_t)tok * KQ + q];
            Xs2[(2*q+0)*64 + r] = pack2_(v.x, v.y);
            Xs2[(2*q+1)*64 + r] = pack2_(v.z, v.w);
        }
    } else {
        constexpr int KQ8 = K / 8;
        for (int idx = tid; idx < 64 * KQ8; idx += 256) {
            const int r = idx & 63, q = idx >> 6;
            union { float4 f; h2_t h[4]; } u;
            u.f = ((const float4*)Xh)[((size_t)b * TT + tbase + r) * KQ8 + q];
            #pragma unroll
            for (int i2 = 0; i2 < 4; ++i2)
                Xs2[(4*q + i2)*64 + r] = u.h[i2];
        }
    }
    // stage W fp16 k-pair-major: Ws2[k2][c]
    {
        constexpr int KQ = K / 4;
        for (int idx = tid; idx < 64 * KQ; idx += 256) {
            const int c = idx & 63, q = idx >> 6;
            float4 v = make_float4(0.f,0.f,0.f,0.f);
            if (c0 + c < GG) v = ((const float4*)W)[(size_t)(c0 + c) * KQ + q];
            Ws2[(2*q+0)*64 + c] = pack2_(v.x, v.y);
            Ws2[(2*q+1)*64 + c] = pack2_(v.z, v.w);
        }
    }
    __syncthreads();

    const int tx = tid & 15, ty = tid >> 4;
    float acc[4][4] = {};
    #pragma unroll 2
    for (int k2 = 0; k2 < K2; ++k2) {
        union { float4 f; h2_t h[4]; } xa, wv;
        xa.f = *(const float4*)(Xs2 + k2*64 + (ty << 2));
        wv.f = *(const float4*)(Ws2 + k2*64 + (tx << 2));
        #pragma unroll
        for (int i = 0; i < 4; ++i)
            #pragma unroll
            for (int j2 = 0; j2 < 4; ++j2)
                acc[i][j2] = fdot2_(xa.h[i], wv.h[j2], acc[i][j2]);
    }

    const int c = c0 + (tx << 2);
    if (c < GG) {
        const float b0v = bias[c], b1v = bias[c+1], b2v = bias[c+2], b3v = bias[c+3];
        const size_t rowB = ((size_t)dir * BB + b) * TC;
        #pragma unroll
        for (int i = 0; i < 4; ++i) {
            const int tloc = (ty << 2) + i;
            union { float2 f; __half2 h[2]; } u;
            u.h[0] = __floats2half2_rn(acc[i][0] + b0v, acc[i][1] + b1v);
            u.h[1] = __floats2half2_rn(acc[i][2] + b2v, acc[i][3] + b3v);
            *(float2*)(gxW + (rowB + tloc) * GG + c) = u.f;
        }
    }
}

// pool_cat = [hb1, hf1, hb0, hf0, avg(80), max(80)] -> fc1(128) -> lrelu -> fc2(1)
__global__ __launch_bounds__(128) void fc_kernel(
    const float* __restrict__ hlast, const float* __restrict__ sumb,
    const float* __restrict__ maxb, const int* __restrict__ lens,
    const float* __restrict__ fc1W, const float* __restrict__ fc1b,
    const float* __restrict__ fc2W, const float* __restrict__ fc2b,
    float* __restrict__ out)
{
    __shared__ float pool[8 * HH];
    __shared__ float red[128];
    const int b = blockIdx.x, tid = threadIdx.x;
    if (tid < HH) {
        pool[tid]        = hlast[(size_t)(3*BB + b) * HH + tid]; // hb1
        pool[HH + tid]   = hlast[(size_t)(2*BB + b) * HH + tid]; // hf1
        pool[2*HH + tid] = hlast[(size_t)(1*BB + b) * HH + tid]; // hb0
        pool[3*HH + tid] = hlast[(size_t)(0*BB + b) * HH + tid]; // hf0
    }
    const float invLen = 1.0f / (float)lens[b];
    if (tid < 2*HH) {
        pool[4*HH + tid] = sumb[(size_t)b * 2*HH + tid] * invLen;
        pool[6*HH + tid] = maxb[(size_t)b * 2*HH + tid];
    }
    __syncthreads();
    float acc = fc1b[tid];
    for (int k = 0; k < 8*HH; ++k)
        acc = fmaf(pool[k], fc1W[(size_t)tid * (8*HH) + k], acc);
    float v = (acc >= 0.0f) ? acc : 0.01f * acc;
    red[tid] = v * fc2W[tid];
    __syncthreads();
    for (int s = 64; s > 0; s >>= 1) {
        if (tid < s) red[tid] += red[tid + s];
        __syncthreads();
    }
    if (tid == 0) out[b] = red[0] + fc2b[0];
}

extern "C" void kernel_launch(void* const* d_in, const int* in_sizes, int n_in,
                              void* d_out, int out_size, void* d_ws, size_t ws_size,
                              hipStream_t stream) {
    const int*   text  = (const int*)d_in[0];
    const int*   lens  = (const int*)d_in[1];
    const float* emb   = (const float*)d_in[2];
    const float* Wih0f = (const float*)d_in[3];
    const float* Whh0f = (const float*)d_in[4];
    const float* bih0f = (const float*)d_in[5];
    const float* bhh0f = (const float*)d_in[6];
    const float* Wih0b = (const float*)d_in[7];
    const float* Whh0b = (const float*)d_in[8];
    const float* bih0b = (const float*)d_in[9];
    const float* bhh0b = (const float*)d_in[10];
    const float* Wih1f = (const float*)d_in[11];
    const float* Whh1f = (const float*)d_in[12];
    const float* bih1f = (const float*)d_in[13];
    const float* bhh1f = (const float*)d_in[14];
    const float* Wih1b = (const float*)d_in[15];
    const float* Whh1b = (const float*)d_in[16];
    const float* bih1b = (const float*)d_in[17];
    const float* bhh1b = (const float*)d_in[18];
    const float* fc1W  = (const float*)d_in[19];
    const float* fc1b  = (const float*)d_in[20];
    const float* fc2W  = (const float*)d_in[21];
    const float* fc2b  = (const float*)d_in[22];
    float* out = (float*)d_out;

    // ws: gx double-buffer fp16 (2 x 15.73MB) | out0 fp16 (41.94MB) | small
    char* p = (char*)d_ws;
    const size_t gxB = (size_t)2 * BB * TC * GG * sizeof(__half);
    __half* gxb0  = (__half*)p;  p += gxB;
    __half* gxb1  = (__half*)p;  p += gxB;
    __half* out0  = (__half*)p;  p += (size_t)BB * TT * 2 * HH * sizeof(__half);
    float*  hcar  = (float*)p;   p += (size_t)2 * BB * HH * sizeof(float);
    float*  hlast = (float*)p;   p += (size_t)4 * BB * HH * sizeof(float);
    float*  sumb  = (float*)p;   p += (size_t)BB * 2 * HH * sizeof(float);
    float*  maxb  = (float*)p;
    __half* gxb[2] = { gxb0, gxb1 };

    const int NG = BB * 2 * 2;   // 2048 gemm blocks
    const int NS = 256;          // 1024 chains / 4 waves per block

    // ---- layer 0 ----
    fused_kernel<EE, true><<<NG, 256, 0, stream>>>(0, 0, 0,
        text, emb, nullptr, Wih0f, bih0f, Wih0b, bih0b,
        gxb[0], gxb[0], Whh0f, bhh0f, Whh0b, bhh0b,
        lens, out0, hcar, hlast, sumb, maxb);
    for (int ci = 1; ci < NC; ++ci)
        fused_kernel<EE, true><<<NS + NG, 256, 0, stream>>>(ci, ci - 1, NS,
            text, emb, nullptr, Wih0f, bih0f, Wih0b, bih0b,
            gxb[ci & 1], gxb[(ci - 1) & 1], Whh0f, bhh0f, Whh0b, bhh0b,
            lens, out0, hcar, hlast, sumb, maxb);
    fused_kernel<EE, true><<<NS, 256, 0, stream>>>(0, NC - 1, NS,
        text, emb, nullptr, Wih0f, bih0f, Wih0b, bih0b,
        gxb[0], gxb[(NC - 1) & 1], Whh0f, bhh0f, Whh0b, bhh0b,
        lens, out0, hcar, hlast, sumb, maxb);

    // ---- layer 1 ----
    fused_kernel<2*HH, false><<<NG, 256, 0, stream>>>(0, 0, 0,
        text, emb, out0, Wih1f, bih1f, Wih1b, bih1b,
        gxb[0], gxb[0], Whh1f, bhh1f, Whh1b, bhh1b,
        lens, out0, hcar, hlast, sumb, maxb);
    for (int ci = 1; ci < NC; ++ci)
        fused_kernel<2*HH, false><<<NS + NG, 256, 0, stream>>>(ci, ci - 1, NS,
            text, emb, out0, Wih1f, bih1f, Wih1b, bih1b,
            gxb[ci & 1], gxb[(ci - 1) & 1], Whh1f, bhh1f, Whh1b, bhh1b,
            lens, out0, hcar, hlast, sumb, maxb);
    fused_kernel<2*HH, false><<<NS, 256, 0, stream>>>(0, NC - 1, NS,
        text, emb, out0, Wih1f, bih1f, Wih1b, bih1b,
        gxb[0], gxb[(NC - 1) & 1], Whh1f, bhh1f, Whh1b, bhh1b,
        lens, out0, hcar, hlast, sumb, maxb);

    // ---- head ----
    fc_kernel<<<BB, 128, 0, stream>>>(hlast, sumb, maxb, lens,
        fc1W, fc1b, fc2W, fc2b, out);
}